// Round 9
// baseline (407.614 us; speedup 1.0000x reference)
//
#include <hip/hip_runtime.h>
#include <hip/hip_bf16.h>
#include <cstdint>
#include <cstddef>

#define NNODES 50000
#define NEDGES 500000
#define ETOT   (NEDGES + NNODES)

typedef __attribute__((ext_vector_type(8))) short short8;
typedef __attribute__((ext_vector_type(8))) unsigned short ushort8v;
typedef __attribute__((ext_vector_type(4))) float floatx4;
typedef __attribute__((ext_vector_type(4))) unsigned short ushort4v;

__device__ __forceinline__ unsigned short f2bf(float f) {
    union { __hip_bfloat16 h; unsigned short u; } cv;
    cv.h = __float2bfloat16(f);
    return cv.u;
}
__device__ __forceinline__ float bf2f(unsigned short u) {
    union { unsigned int i; float f; } cv;
    cv.i = ((unsigned int)u) << 16;
    return cv.f;
}

// ================= bf16 MFMA GEMM: C/Cb = op(A @ Bt^T + bias) =================
#define GBM 128
#define GBN 64
#define GBK 32

__global__ __launch_bounds__(256, 4) void gemm_mfma(
    const unsigned short* __restrict__ A, int lda,
    const unsigned short* __restrict__ Bt,
    float* __restrict__ C,
    unsigned short* __restrict__ Cb,
    const float* __restrict__ bias,
    float* __restrict__ colsum, float* __restrict__ colsq,
    const float* __restrict__ att_s, const float* __restrict__ att_d,
    float* __restrict__ as_out, float* __restrict__ ad_out, int Hheads,
    int M, int N, int K, int do_relu)
{
    __shared__ __attribute__((aligned(16))) unsigned short Alds[GBM * GBK];
    __shared__ __attribute__((aligned(16))) unsigned short Blds[GBN * GBK];
    __shared__ float scol[GBN], sqcol[GBN];

    int tid = threadIdx.x;
    int wave = tid >> 6, lane = tid & 63;
    int row0 = blockIdx.y * GBM;
    int col0 = blockIdx.x * GBN;
    int m = lane & 15, q = lane >> 4;

    floatx4 acc[2][4] = {};

    for (int k0 = 0; k0 < K; k0 += GBK) {
        #pragma unroll
        for (int i = 0; i < 2; ++i) {
            int c = tid + i * 256;
            int r = c >> 2, off = (c & 3) * 8;
            int gr = row0 + r;
            short8 v = {};
            if (gr < M) v = *(const short8*)(A + (size_t)gr * lda + k0 + off);
            *(short8*)(Alds + r * GBK + off) = v;
        }
        {
            int r = tid >> 2, off = (tid & 3) * 8;
            short8 v = *(const short8*)(Bt + (size_t)(col0 + r) * K + k0 + off);
            *(short8*)(Blds + r * GBK + off) = v;
        }
        __syncthreads();

        short8 a0 = *(const short8*)(Alds + (wave * 32 + m) * GBK + q * 8);
        short8 a1 = *(const short8*)(Alds + (wave * 32 + 16 + m) * GBK + q * 8);
        #pragma unroll
        for (int ct = 0; ct < 4; ++ct) {
            short8 b = *(const short8*)(Blds + (ct * 16 + m) * GBK + q * 8);
            acc[0][ct] = __builtin_amdgcn_mfma_f32_16x16x32_bf16(a0, b, acc[0][ct], 0, 0, 0);
            acc[1][ct] = __builtin_amdgcn_mfma_f32_16x16x32_bf16(a1, b, acc[1][ct], 0, 0, 0);
        }
        __syncthreads();
    }

    float ps[4] = {}, pq[4] = {};
    #pragma unroll
    for (int rt = 0; rt < 2; ++rt) {
        #pragma unroll
        for (int r = 0; r < 4; ++r) {
            int gr = row0 + wave * 32 + rt * 16 + q * 4 + r;
            float ds = 0.f, dd = 0.f;
            #pragma unroll
            for (int ct = 0; ct < 4; ++ct) {
                int gc = col0 + ct * 16 + m;
                float v = acc[rt][ct][r];
                if (gc < N) {
                    if (att_s != nullptr) { ds += v * att_s[gc]; dd += v * att_d[gc]; }
                    float vb = v;
                    if (bias != nullptr) vb += bias[gc];
                    if (do_relu) vb = fmaxf(vb, 0.f);
                    if (gr < M) {
                        if (C  != nullptr) C[(size_t)gr * N + gc] = vb;
                        if (Cb != nullptr) Cb[(size_t)gr * N + gc] = f2bf(vb);
                        ps[ct] += vb; pq[ct] += vb * vb;
                    }
                }
            }
            if (att_s != nullptr) {
                #pragma unroll
                for (int off = 1; off < 16; off <<= 1) {
                    ds += __shfl_xor(ds, off);
                    dd += __shfl_xor(dd, off);
                }
                if (m == 0 && gr < M) {
                    int head = col0 >> 7;
                    atomicAdd(&as_out[gr * Hheads + head], ds);
                    atomicAdd(&ad_out[gr * Hheads + head], dd);
                }
            }
        }
    }
    if (colsum != nullptr) {
        if (tid < GBN) { scol[tid] = 0.f; sqcol[tid] = 0.f; }
        __syncthreads();
        #pragma unroll
        for (int ct = 0; ct < 4; ++ct) {
            atomicAdd(&scol[ct * 16 + m], ps[ct]);
            atomicAdd(&sqcol[ct * 16 + m], pq[ct]);
        }
        __syncthreads();
        if (tid < GBN) {
            int gc = col0 + tid;
            if (gc < N) {
                atomicAdd(&colsum[gc], scol[tid]);
                atomicAdd(&colsq[gc], sqcol[tid]);
            }
        }
    }
}

// ================= casts =================
__global__ void cast_x_k(const float* __restrict__ x, unsigned short* __restrict__ xb, int total4) {
    int i = blockIdx.x * blockDim.x + threadIdx.x;
    if (i >= total4) return;
    const float4 v = ((const float4*)x)[i];
    ushort4v o;
    o.x = f2bf(v.x); o.y = f2bf(v.y); o.z = f2bf(v.z); o.w = f2bf(v.w);
    ((ushort4v*)xb)[i] = o;
}

__global__ void cast_weights(const float* __restrict__ W1, const float* __restrict__ W2,
                             const float* __restrict__ Wl,
                             unsigned short* __restrict__ W1t, unsigned short* __restrict__ W2t,
                             unsigned short* __restrict__ Wlt) {
    int i = blockIdx.x * 256 + threadIdx.x;
    if (i < 32768) {                                   // W1t [256][128], W1 [128][256]
        int n = i >> 7, k = i & 127;
        W1t[i] = f2bf(W1[k * 256 + n]);
    } else if (i < 65536) {                            // W2t [128][256], W2 [256][128]
        int j = i - 32768;
        int n = j >> 8, k = j & 255;
        W2t[j] = f2bf(W2[k * 128 + n]);
    } else if (i < 114688) {                           // Wlt [128][384], Wl [384][96]
        int j = i - 65536;
        int n = j / 384, k = j % 384;
        Wlt[j] = (n < 96) ? f2bf(Wl[(size_t)k * 96 + n]) : (unsigned short)0;
    }
}

// ================= fused BN-finalize + weight-fold kernels =================
__global__ void bnfold_a(const float* __restrict__ csum, const float* __restrict__ csq,
                         const float* __restrict__ gamma, const float* __restrict__ beta,
                         const float* __restrict__ Wa, const float* __restrict__ ba,
                         unsigned short* __restrict__ Wat2, float* __restrict__ ba_f) {
    __shared__ float scl[96], shf[96];
    int tid = threadIdx.x;
    if (tid < 96) {
        float mu  = csum[tid] / (float)NNODES;
        float var = csq[tid] / (float)NNODES - mu * mu;
        if (var < 0.f) var = 0.f;
        float sc = gamma[tid] * rsqrtf(var + 1e-5f);
        scl[tid] = sc; shf[tid] = beta[tid] - mu * sc;
    }
    __syncthreads();
    for (int idx = tid; idx < 128 * 96; idx += 256) {
        int n = idx / 96, k = idx % 96;
        Wat2[idx] = (n < 96) ? f2bf(scl[k] * Wa[k * 96 + n]) : (unsigned short)0;
    }
    if (tid < 96) {
        float s = ba[tid];
        for (int k = 0; k < 96; ++k) s += shf[k] * Wa[k * 96 + tid];
        ba_f[tid] = s;
    }
}

__global__ void bnfold_b(const float* __restrict__ csum, const float* __restrict__ csq,
                         const float* __restrict__ gamma, const float* __restrict__ beta,
                         const float* __restrict__ Wb, const float* __restrict__ bb,
                         unsigned short* __restrict__ Wbt, float* __restrict__ bb_f) {
    __shared__ float scl[96], shf[96];
    int tid = threadIdx.x;
    if (tid < 96) {
        float mu  = csum[tid] / (float)NNODES;
        float var = csq[tid] / (float)NNODES - mu * mu;
        if (var < 0.f) var = 0.f;
        float sc = gamma[tid] * rsqrtf(var + 1e-5f);
        scl[tid] = sc; shf[tid] = beta[tid] - mu * sc;
    }
    __syncthreads();
    for (int idx = tid; idx < 64 * 96; idx += 256) {
        int n = idx / 96, k = idx % 96;
        Wbt[idx] = (n < 2) ? f2bf(scl[k] * Wb[k * 2 + n]) : (unsigned short)0;
    }
    if (tid < 2) {
        float s = bb[tid];
        for (int k = 0; k < 96; ++k) s += shf[k] * Wb[k * 2 + tid];
        bb_f[tid] = s;
    }
}

__global__ void bn_fin_apply(const float* __restrict__ csum, const float* __restrict__ csq,
                             const float* __restrict__ gamma, const float* __restrict__ beta,
                             float* __restrict__ y, int total) {
    int i = blockIdx.x * blockDim.x + threadIdx.x;
    if (i >= total) return;
    int j = i & 1;
    float mu  = csum[j] / (float)NNODES;
    float var = csq[j] / (float)NNODES - mu * mu;
    if (var < 0.f) var = 0.f;
    float sc = gamma[j] * rsqrtf(var + 1e-5f);
    float sh = beta[j] - mu * sc;
    y[i] = y[i] * sc + sh;
}

__device__ __forceinline__ void edge_src_dst(const int* ei, int e, int& src, int& dst) {
    if (e < NEDGES) { src = ei[e]; dst = ei[NEDGES + e]; }
    else { src = e - NEDGES; dst = src; }
}

// ================= CSR build =================
__global__ __launch_bounds__(256) void csr_count(const int* __restrict__ ei, int* __restrict__ cnt) {
    int e = blockIdx.x * blockDim.x + threadIdx.x;
    if (e >= ETOT) return;
    int src, dst; edge_src_dst(ei, e, src, dst); (void)src;
    atomicAdd(&cnt[dst], 1);
}

#define SCAN_CH 1024
#define SCAN_NB ((NNODES + SCAN_CH - 1) / SCAN_CH)   // 49

__global__ __launch_bounds__(256) void scan1(const int* __restrict__ cnt, int* __restrict__ part) {
    int t = threadIdx.x;
    int base = blockIdx.x * SCAN_CH + t * 4;
    int4 v = {0, 0, 0, 0};
    if (base + 3 < NNODES) v = *(const int4*)(cnt + base);
    else {
        if (base + 0 < NNODES) v.x = cnt[base + 0];
        if (base + 1 < NNODES) v.y = cnt[base + 1];
        if (base + 2 < NNODES) v.z = cnt[base + 2];
        if (base + 3 < NNODES) v.w = cnt[base + 3];
    }
    int s = v.x + v.y + v.z + v.w;
    __shared__ int sm[256];
    sm[t] = s;
    __syncthreads();
    for (int off = 128; off > 0; off >>= 1) {
        if (t < off) sm[t] += sm[t + off];
        __syncthreads();
    }
    if (t == 0) part[blockIdx.x] = sm[0];
}

__global__ void scan2(int* __restrict__ part, int* __restrict__ rowstart) {
    int lane = threadIdx.x;
    int v = (lane < SCAN_NB) ? part[lane] : 0;
    #pragma unroll
    for (int off = 1; off < 64; off <<= 1) {
        int t = __shfl_up(v, off);
        if (lane >= off) v += t;
    }
    int ex = __shfl_up(v, 1);
    if (lane == 0) ex = 0;
    if (lane < SCAN_NB) part[lane] = ex;
    if (lane == 0) rowstart[NNODES] = ETOT;
}

__global__ __launch_bounds__(256) void scan3(const int* __restrict__ cnt, const int* __restrict__ part,
                                             int* __restrict__ rowstart, int* __restrict__ cursor) {
    int t = threadIdx.x;
    int base = blockIdx.x * SCAN_CH + t * 4;
    int4 v = {0, 0, 0, 0};
    if (base + 3 < NNODES) v = *(const int4*)(cnt + base);
    else {
        if (base + 0 < NNODES) v.x = cnt[base + 0];
        if (base + 1 < NNODES) v.y = cnt[base + 1];
        if (base + 2 < NNODES) v.z = cnt[base + 2];
        if (base + 3 < NNODES) v.w = cnt[base + 3];
    }
    int s = v.x + v.y + v.z + v.w;
    __shared__ int sm[2][256];
    sm[0][t] = s;
    __syncthreads();
    int cur = 0;
    #pragma unroll
    for (int off = 1; off < 256; off <<= 1) {
        int nxt = cur ^ 1;
        int val = sm[cur][t];
        if (t >= off) val += sm[cur][t - off];
        sm[nxt][t] = val;
        __syncthreads();
        cur = nxt;
    }
    int p = sm[cur][t] - s + part[blockIdx.x];
    if (base + 0 < NNODES) { rowstart[base + 0] = p; cursor[base + 0] = p; } p += v.x;
    if (base + 1 < NNODES) { rowstart[base + 1] = p; cursor[base + 1] = p; } p += v.y;
    if (base + 2 < NNODES) { rowstart[base + 2] = p; cursor[base + 2] = p; } p += v.z;
    if (base + 3 < NNODES) { rowstart[base + 3] = p; cursor[base + 3] = p; }
}

__global__ __launch_bounds__(256) void csr_fill(const int* __restrict__ ei,
                                                int* __restrict__ cursor,
                                                int* __restrict__ esrc) {
    int e = blockIdx.x * blockDim.x + threadIdx.x;
    if (e >= ETOT) return;
    int src, dst; edge_src_dst(ei, e, src, dst);
    int pos = atomicAdd(&cursor[dst], 1);
    esrc[pos] = src;
}

// ================= per-edge softmax weights (16-lane group per node) =================
__global__ __launch_bounds__(256) void edge_w_h2(
    const int* __restrict__ rowstart, const int* __restrict__ esrc,
    const float* __restrict__ a_src, const float* __restrict__ a_dst,
    float2* __restrict__ wedge)
{
    int g  = threadIdx.x >> 4;
    int sl = threadIdx.x & 15;
    int n = blockIdx.x * 16 + g;
    if (n >= NNODES) return;
    int beg = rowstart[n], deg = rowstart[n + 1] - beg;
    float ad0 = a_dst[n * 2], ad1 = a_dst[n * 2 + 1];

    float m0 = -1e30f, m1 = -1e30f;
    for (int i = sl; i < deg; i += 16) {
        int s = esrc[beg + i];
        float l0 = a_src[s * 2] + ad0;     l0 = l0 >= 0.f ? l0 : 0.2f * l0;
        float l1 = a_src[s * 2 + 1] + ad1; l1 = l1 >= 0.f ? l1 : 0.2f * l1;
        m0 = fmaxf(m0, l0); m1 = fmaxf(m1, l1);
    }
    #pragma unroll
    for (int off = 1; off < 16; off <<= 1) {
        m0 = fmaxf(m0, __shfl_xor(m0, off));
        m1 = fmaxf(m1, __shfl_xor(m1, off));
    }
    float s0 = 0.f, s1 = 0.f;
    for (int i = sl; i < deg; i += 16) {
        int s = esrc[beg + i];
        float l0 = a_src[s * 2] + ad0;     l0 = l0 >= 0.f ? l0 : 0.2f * l0;
        float l1 = a_src[s * 2 + 1] + ad1; l1 = l1 >= 0.f ? l1 : 0.2f * l1;
        float e0 = __expf(l0 - m0), e1 = __expf(l1 - m1);
        s0 += e0; s1 += e1;
        float2 w; w.x = e0; w.y = e1;
        wedge[beg + i] = w;
    }
    #pragma unroll
    for (int off = 1; off < 16; off <<= 1) {
        s0 += __shfl_xor(s0, off);
        s1 += __shfl_xor(s1, off);
    }
    float inv0 = 1.f / (s0 + 1e-16f), inv1 = 1.f / (s1 + 1e-16f);
    for (int i = sl; i < deg; i += 16) {
        float2 w = wedge[beg + i];
        w.x *= inv0; w.y *= inv1;
        wedge[beg + i] = w;
    }
}

__global__ __launch_bounds__(256) void edge_w_h1(
    const int* __restrict__ rowstart, const int* __restrict__ esrc,
    const float* __restrict__ a_src, const float* __restrict__ a_dst,
    float* __restrict__ wedge)
{
    int g  = threadIdx.x >> 4;
    int sl = threadIdx.x & 15;
    int n = blockIdx.x * 16 + g;
    if (n >= NNODES) return;
    int beg = rowstart[n], deg = rowstart[n + 1] - beg;
    float ad0 = a_dst[n];

    float m0 = -1e30f;
    for (int i = sl; i < deg; i += 16) {
        int s = esrc[beg + i];
        float l0 = a_src[s] + ad0; l0 = l0 >= 0.f ? l0 : 0.2f * l0;
        m0 = fmaxf(m0, l0);
    }
    #pragma unroll
    for (int off = 1; off < 16; off <<= 1) m0 = fmaxf(m0, __shfl_xor(m0, off));
    float s0 = 0.f;
    for (int i = sl; i < deg; i += 16) {
        int s = esrc[beg + i];
        float l0 = a_src[s] + ad0; l0 = l0 >= 0.f ? l0 : 0.2f * l0;
        float e0 = __expf(l0 - m0);
        s0 += e0;
        wedge[beg + i] = e0;
    }
    #pragma unroll
    for (int off = 1; off < 16; off <<= 1) s0 += __shfl_xor(s0, off);
    float inv0 = 1.f / (s0 + 1e-16f);
    for (int i = sl; i < deg; i += 16) wedge[beg + i] *= inv0;
}

// ================= pure gather kernels =================
// conv1 (H=2, 256 feats): 2 groups x 32 lanes x 16 B, unroll 2.
__global__ __launch_bounds__(256) void gat_gather_h2(
    const int* __restrict__ rowstart, const int* __restrict__ esrc,
    const unsigned short* __restrict__ hb, const float2* __restrict__ wedge,
    const float* __restrict__ bias, unsigned short* __restrict__ xcat)
{
    int n = (blockIdx.x * blockDim.x + threadIdx.x) >> 6;
    int lane = threadIdx.x & 63;
    if (n >= NNODES) return;
    int beg = rowstart[n], deg = rowstart[n + 1] - beg;
    const int* es = esrc + beg;
    const float2* we = wedge + beg;
    int g = lane >> 5, sl = lane & 31, head = sl >> 4;

    float acc[8] = {}, acc2[8] = {};
    for (int idx = g; idx < deg; idx += 4) {
        int sA = es[idx];
        float2 wv = we[idx];
        float wA = head ? wv.y : wv.x;
        const ushort8v hvA = *(const ushort8v*)(hb + (size_t)sA * 256 + sl * 8);
        int i2 = idx + 2;
        if (i2 < deg) {
            int sB = es[i2];
            float2 wv2 = we[i2];
            float wB = head ? wv2.y : wv2.x;
            const ushort8v hvB = *(const ushort8v*)(hb + (size_t)sB * 256 + sl * 8);
            #pragma unroll
            for (int j = 0; j < 8; ++j) acc2[j] += wB * bf2f(hvB[j]);
        }
        #pragma unroll
        for (int j = 0; j < 8; ++j) acc[j] += wA * bf2f(hvA[j]);
    }
    #pragma unroll
    for (int j = 0; j < 8; ++j) acc[j] += acc2[j];
    #pragma unroll
    for (int j = 0; j < 8; ++j) acc[j] += __shfl_xor(acc[j], 32);
    if (g == 0) {
        ushort8v o;
        #pragma unroll
        for (int j = 0; j < 8; ++j) o[j] = f2bf(acc[j] + bias[sl * 8 + j]);
        *(ushort8v*)(xcat + (size_t)n * 384 + sl * 8) = o;
    }
}

// conv2 (H=1, 128 feats): 4 groups x 16 lanes x 16 B, unroll 2.
__global__ __launch_bounds__(256) void gat_gather_h1(
    const int* __restrict__ rowstart, const int* __restrict__ esrc,
    const unsigned short* __restrict__ hb, const float* __restrict__ wedge,
    const float* __restrict__ bias, unsigned short* __restrict__ xcat)
{
    int n = (blockIdx.x * blockDim.x + threadIdx.x) >> 6;
    int lane = threadIdx.x & 63;
    if (n >= NNODES) return;
    int beg = rowstart[n], deg = rowstart[n + 1] - beg;
    const int* es = esrc + beg;
    const float* we = wedge + beg;
    int g = lane >> 4, sl = lane & 15;

    float acc[8] = {}, acc2[8] = {};
    for (int idx = g; idx < deg; idx += 8) {
        int sA = es[idx];
        float wA = we[idx];
        const ushort8v hvA = *(const ushort8v*)(hb + (size_t)sA * 128 + sl * 8);
        int i2 = idx + 4;
        if (i2 < deg) {
            int sB = es[i2];
            float wB = we[i2];
            const ushort8v hvB = *(const ushort8v*)(hb + (size_t)sB * 128 + sl * 8);
            #pragma unroll
            for (int j = 0; j < 8; ++j) acc2[j] += wB * bf2f(hvB[j]);
        }
        #pragma unroll
        for (int j = 0; j < 8; ++j) acc[j] += wA * bf2f(hvA[j]);
    }
    #pragma unroll
    for (int j = 0; j < 8; ++j) acc[j] += acc2[j];
    #pragma unroll
    for (int j = 0; j < 8; ++j) acc[j] += __shfl_xor(acc[j], 16);
    #pragma unroll
    for (int j = 0; j < 8; ++j) acc[j] += __shfl_xor(acc[j], 32);
    if (g == 0) {
        ushort8v o;
        #pragma unroll
        for (int j = 0; j < 8; ++j) o[j] = f2bf(acc[j] + bias[sl * 8 + j]);
        *(ushort8v*)(xcat + (size_t)n * 384 + 256 + sl * 8) = o;
    }
}

extern "C" void kernel_launch(void* const* d_in, const int* in_sizes, int n_in,
                              void* d_out, int out_size, void* d_ws, size_t ws_size,
                              hipStream_t stream) {
    const float* x        = (const float*)d_in[0];
    const int*   ei       = (const int*)d_in[1];
    const float* W1       = (const float*)d_in[2];
    const float* att_src1 = (const float*)d_in[3];
    const float* att_dst1 = (const float*)d_in[4];
    const float* bias1    = (const float*)d_in[5];
    const float* W2       = (const float*)d_in[6];
    const float* att_src2 = (const float*)d_in[7];
    const float* att_dst2 = (const float*)d_in[8];
    const float* bias2    = (const float*)d_in[9];
    const float* Wl       = (const float*)d_in[10];
    const float* bl       = (const float*)d_in[11];
    const float* gl       = (const float*)d_in[12];
    const float* betal    = (const float*)d_in[13];
    const float* Wa       = (const float*)d_in[14];
    const float* ba       = (const float*)d_in[15];
    const float* ga       = (const float*)d_in[16];
    const float* betaa    = (const float*)d_in[17];
    const float* Wb       = (const float*)d_in[18];
    const float* bb       = (const float*)d_in[19];
    const float* gb       = (const float*)d_in[20];
    const float* betab    = (const float*)d_in[21];
    float* out = (float*)d_out;
    char* ws = (char*)d_ws;

    const int N = NNODES;

    // ---------- workspace layout (bytes) ----------
    // region [0, 9.6MB): wedge (gather phase) then y2b (MLP phase) — lifetimes disjoint
    const size_t offWedge= 0;            //  4.4 MB: wedge f32x2[ETOT] / f32[ETOT]
    const size_t offY2b  = 0;            //  9.6 MB: y2b bf16 [50000][96]
    const size_t offXcat = 19200000;     // 38.4 MB: xcat bf16 [50000][384]
    const size_t offXb   = 57600000;     // 12.8 MB: xb bf16 -> hb2 bf16 [50000][128]
    const size_t offY1b  = 70400000;     //  9.6 MB: y1b bf16 [50000][96]
    const size_t offHb1  = 80000000;     // 25.6 MB: hb1 bf16 [50000][256]
    const size_t offW1t  = 105600000;    // 64 KB
    const size_t offW2t  = 105665536;    // 64 KB
    const size_t offWlt  = 105731072;    // 96 KB
    const size_t offWat2 = 105829376;    // folded Wa bf16 [128][96]
    const size_t offWbt  = 105853952;    // folded Wb bf16 [64][96]
    const size_t offBaf  = 105866240;    // folded ba [96] f32
    const size_t offBbf  = 105866640;    // folded bb [2] f32
    const size_t offRow  = 106000000;    // cnt -> rowstart [N+1] ints
    const size_t offCur  = 106200128;    // cursor [N] ints
    const size_t offEsrc = 106400832;    // esrc [ETOT] ints
    const size_t offPart = 108700000;    // scan partials [64] ints
    const size_t offAs1  = 108800000;    // a_src1 [N*2] f32
    const size_t offAd1  = 109200000;
    const size_t offAs2  = 109600000;
    const size_t offAd2  = 109800000;
    const size_t offSt   = 110000000;    // stats

    float2* wedge2 = (float2*)(ws + offWedge);
    float*  wedge1 = (float*)(ws + offWedge);
    unsigned short* y2b  = (unsigned short*)(ws + offY2b);
    unsigned short* xcat = (unsigned short*)(ws + offXcat);
    unsigned short* xb   = (unsigned short*)(ws + offXb);
    unsigned short* hb2  = (unsigned short*)(ws + offXb);
    unsigned short* y1b  = (unsigned short*)(ws + offY1b);
    unsigned short* hb1  = (unsigned short*)(ws + offHb1);
    unsigned short* W1t  = (unsigned short*)(ws + offW1t);
    unsigned short* W2t  = (unsigned short*)(ws + offW2t);
    unsigned short* Wlt  = (unsigned short*)(ws + offWlt);
    unsigned short* Wat2 = (unsigned short*)(ws + offWat2);
    unsigned short* Wbt  = (unsigned short*)(ws + offWbt);
    float* ba_f = (float*)(ws + offBaf);
    float* bb_f = (float*)(ws + offBbf);
    int* rowst  = (int*)(ws + offRow);
    int* cursor = (int*)(ws + offCur);
    int* esrc   = (int*)(ws + offEsrc);
    int* part   = (int*)(ws + offPart);
    float* as1  = (float*)(ws + offAs1);
    float* ad1  = (float*)(ws + offAd1);
    float* as2  = (float*)(ws + offAs2);
    float* ad2  = (float*)(ws + offAd2);

    float* csum_l = (float*)(ws + offSt + 0);
    float* csq_l  = (float*)(ws + offSt + 512);
    float* csum_a = (float*)(ws + offSt + 2048);
    float* csq_a  = (float*)(ws + offSt + 2560);
    float* csum_b = (float*)(ws + offSt + 4096);
    float* csq_b  = (float*)(ws + offSt + 4608);

    hipMemsetAsync(ws + offRow, 0, (NNODES + 1) * sizeof(int), stream);
    hipMemsetAsync(ws + offAs1, 0, (offSt + 6144) - offAs1, stream);

    dim3 blk(256);
    int edgeBlocks  = (ETOT + 255) / 256;
    int waveBlocksN = (N + 3) / 4;
    int grpBlocksN  = (N + 15) / 16;

    // ---- casts ----
    cast_x_k<<<(N * 128 / 4 + 255) / 256, blk, 0, stream>>>(x, xb, N * 128 / 4);
    cast_weights<<<(114688 + 255) / 256, blk, 0, stream>>>(W1, W2, Wl, W1t, W2t, Wlt);

    // ---- CSR build ----
    csr_count<<<edgeBlocks, blk, 0, stream>>>(ei, rowst);
    scan1<<<SCAN_NB, blk, 0, stream>>>(rowst, part);
    scan2<<<1, 64, 0, stream>>>(part, rowst);
    scan3<<<SCAN_NB, blk, 0, stream>>>(rowst, part, rowst, cursor);
    csr_fill<<<edgeBlocks, blk, 0, stream>>>(ei, cursor, esrc);

    // ---- conv1: hb1 = bf16(xb @ W1), fused att dots; weights; gather ----
    gemm_mfma<<<dim3(4, (N + GBM - 1) / GBM), blk, 0, stream>>>(
        xb, 128, W1t, nullptr, hb1, nullptr, nullptr, nullptr,
        att_src1, att_dst1, as1, ad1, 2, N, 256, 128, 0);
    edge_w_h2<<<grpBlocksN, blk, 0, stream>>>(rowst, esrc, as1, ad1, wedge2);
    gat_gather_h2<<<waveBlocksN, blk, 0, stream>>>(rowst, esrc, hb1, wedge2, bias1, xcat);

    // ---- conv2: hb2 = bf16(xcat[:, :256] @ W2), fused att dots; weights; gather ----
    gemm_mfma<<<dim3(2, (N + GBM - 1) / GBM), blk, 0, stream>>>(
        xcat, 384, W2t, nullptr, hb2, nullptr, nullptr, nullptr,
        att_src2, att_dst2, as2, ad2, 1, N, 128, 256, 0);
    edge_w_h1<<<grpBlocksN, blk, 0, stream>>>(rowst, esrc, as2, ad2, wedge1);
    gat_gather_h1<<<waveBlocksN, blk, 0, stream>>>(rowst, esrc, hb2, wedge1, bias2, xcat);

    // ---- lin1: y1b = bf16(relu(xcat @ Wl + bl)), stats; fold BN into Wa ----
    gemm_mfma<<<dim3(2, (N + GBM - 1) / GBM), blk, 0, stream>>>(
        xcat, 384, Wlt, nullptr, y1b, bl, csum_l, csq_l,
        nullptr, nullptr, nullptr, nullptr, 0, N, 96, 384, 1);
    bnfold_a<<<1, 256, 0, stream>>>(csum_l, csq_l, gl, betal, Wa, ba, Wat2, ba_f);

    // ---- mlp1 layer 1: y2b = bf16(relu(y1b @ Wa' + ba')), stats; fold BN into Wb ----
    gemm_mfma<<<dim3(2, (N + GBM - 1) / GBM), blk, 0, stream>>>(
        y1b, 96, Wat2, nullptr, y2b, ba_f, csum_a, csq_a,
        nullptr, nullptr, nullptr, nullptr, 0, N, 96, 96, 1);
    bnfold_b<<<1, 256, 0, stream>>>(csum_a, csq_a, ga, betaa, Wb, bb, Wbt, bb_f);

    // ---- mlp1 layer 2: out = relu(y2b @ Wb' + bb'), stats (MFMA, N=2) ----
    gemm_mfma<<<dim3(1, (N + GBM - 1) / GBM), blk, 0, stream>>>(
        y2b, 96, Wbt, out, nullptr, bb_f, csum_b, csq_b,
        nullptr, nullptr, nullptr, nullptr, 0, N, 2, 96, 1);

    // ---- final BN (fused finalize+apply) ----
    bn_fin_apply<<<(N * 2 + 255) / 256, blk, 0, stream>>>(csum_b, csq_b, gb, betab, out, N * 2);
}

// Round 10
// 394.968 us; speedup vs baseline: 1.0320x; 1.0320x over previous
//
#include <hip/hip_runtime.h>
#include <hip/hip_bf16.h>
#include <cstdint>
#include <cstddef>

#define NNODES 50000
#define NEDGES 500000
#define ETOT   (NEDGES + NNODES)

typedef __attribute__((ext_vector_type(8))) short short8;
typedef __attribute__((ext_vector_type(8))) unsigned short ushort8v;
typedef __attribute__((ext_vector_type(4))) float floatx4;
typedef __attribute__((ext_vector_type(4))) unsigned short ushort4v;

__device__ __forceinline__ unsigned short f2bf(float f) {
    union { __hip_bfloat16 h; unsigned short u; } cv;
    cv.h = __float2bfloat16(f);
    return cv.u;
}
__device__ __forceinline__ float bf2f(unsigned short u) {
    union { unsigned int i; float f; } cv;
    cv.i = ((unsigned int)u) << 16;
    return cv.f;
}

// ================= bf16 MFMA GEMM: C/Cb = op(A @ Bt^T + bias) =================
#define GBM 128
#define GBN 64
#define GBK 32

__global__ __launch_bounds__(256, 4) void gemm_mfma(
    const unsigned short* __restrict__ A, int lda,
    const unsigned short* __restrict__ Bt,
    float* __restrict__ C,
    unsigned short* __restrict__ Cb,
    const float* __restrict__ bias,
    float* __restrict__ colsum, float* __restrict__ colsq,
    const float* __restrict__ att_s, const float* __restrict__ att_d,
    float* __restrict__ as_out, float* __restrict__ ad_out, int Hheads,
    int M, int N, int K, int do_relu)
{
    __shared__ __attribute__((aligned(16))) unsigned short Alds[GBM * GBK];
    __shared__ __attribute__((aligned(16))) unsigned short Blds[GBN * GBK];
    __shared__ float scol[GBN], sqcol[GBN];

    int tid = threadIdx.x;
    int wave = tid >> 6, lane = tid & 63;
    int row0 = blockIdx.y * GBM;
    int col0 = blockIdx.x * GBN;
    int m = lane & 15, q = lane >> 4;

    floatx4 acc[2][4] = {};

    for (int k0 = 0; k0 < K; k0 += GBK) {
        #pragma unroll
        for (int i = 0; i < 2; ++i) {
            int c = tid + i * 256;
            int r = c >> 2, off = (c & 3) * 8;
            int gr = row0 + r;
            short8 v = {};
            if (gr < M) v = *(const short8*)(A + (size_t)gr * lda + k0 + off);
            *(short8*)(Alds + r * GBK + off) = v;
        }
        {
            int r = tid >> 2, off = (tid & 3) * 8;
            short8 v = *(const short8*)(Bt + (size_t)(col0 + r) * K + k0 + off);
            *(short8*)(Blds + r * GBK + off) = v;
        }
        __syncthreads();

        short8 a0 = *(const short8*)(Alds + (wave * 32 + m) * GBK + q * 8);
        short8 a1 = *(const short8*)(Alds + (wave * 32 + 16 + m) * GBK + q * 8);
        #pragma unroll
        for (int ct = 0; ct < 4; ++ct) {
            short8 b = *(const short8*)(Blds + (ct * 16 + m) * GBK + q * 8);
            acc[0][ct] = __builtin_amdgcn_mfma_f32_16x16x32_bf16(a0, b, acc[0][ct], 0, 0, 0);
            acc[1][ct] = __builtin_amdgcn_mfma_f32_16x16x32_bf16(a1, b, acc[1][ct], 0, 0, 0);
        }
        __syncthreads();
    }

    float ps[4] = {}, pq[4] = {};
    #pragma unroll
    for (int rt = 0; rt < 2; ++rt) {
        #pragma unroll
        for (int r = 0; r < 4; ++r) {
            int gr = row0 + wave * 32 + rt * 16 + q * 4 + r;
            float ds = 0.f, dd = 0.f;
            #pragma unroll
            for (int ct = 0; ct < 4; ++ct) {
                int gc = col0 + ct * 16 + m;
                float v = acc[rt][ct][r];
                if (gc < N) {
                    if (att_s != nullptr) { ds += v * att_s[gc]; dd += v * att_d[gc]; }
                    float vb = v;
                    if (bias != nullptr) vb += bias[gc];
                    if (do_relu) vb = fmaxf(vb, 0.f);
                    if (gr < M) {
                        if (C  != nullptr) C[(size_t)gr * N + gc] = vb;
                        if (Cb != nullptr) Cb[(size_t)gr * N + gc] = f2bf(vb);
                        ps[ct] += vb; pq[ct] += vb * vb;
                    }
                }
            }
            if (att_s != nullptr) {
                #pragma unroll
                for (int off = 1; off < 16; off <<= 1) {
                    ds += __shfl_xor(ds, off);
                    dd += __shfl_xor(dd, off);
                }
                if (m == 0 && gr < M) {
                    int head = col0 >> 7;
                    atomicAdd(&as_out[gr * Hheads + head], ds);
                    atomicAdd(&ad_out[gr * Hheads + head], dd);
                }
            }
        }
    }
    if (colsum != nullptr) {
        if (tid < GBN) { scol[tid] = 0.f; sqcol[tid] = 0.f; }
        __syncthreads();
        #pragma unroll
        for (int ct = 0; ct < 4; ++ct) {
            atomicAdd(&scol[ct * 16 + m], ps[ct]);
            atomicAdd(&sqcol[ct * 16 + m], pq[ct]);
        }
        __syncthreads();
        if (tid < GBN) {
            int gc = col0 + tid;
            if (gc < N) {
                atomicAdd(&colsum[gc], scol[tid]);
                atomicAdd(&colsq[gc], sqcol[tid]);
            }
        }
    }
}

// ================= casts =================
__global__ void cast_x_k(const float* __restrict__ x, unsigned short* __restrict__ xb, int total4) {
    int i = blockIdx.x * blockDim.x + threadIdx.x;
    if (i >= total4) return;
    const float4 v = ((const float4*)x)[i];
    ushort4v o;
    o.x = f2bf(v.x); o.y = f2bf(v.y); o.z = f2bf(v.z); o.w = f2bf(v.w);
    ((ushort4v*)xb)[i] = o;
}

__global__ void cast_weights(const float* __restrict__ W1, const float* __restrict__ W2,
                             const float* __restrict__ Wl,
                             unsigned short* __restrict__ W1t, unsigned short* __restrict__ W2t,
                             unsigned short* __restrict__ Wlt) {
    int i = blockIdx.x * 256 + threadIdx.x;
    if (i < 32768) {                                   // W1t [256][128], W1 [128][256]
        int n = i >> 7, k = i & 127;
        W1t[i] = f2bf(W1[k * 256 + n]);
    } else if (i < 65536) {                            // W2t [128][256], W2 [256][128]
        int j = i - 32768;
        int n = j >> 8, k = j & 255;
        W2t[j] = f2bf(W2[k * 128 + n]);
    } else if (i < 114688) {                           // Wlt [128][384], Wl [384][96]
        int j = i - 65536;
        int n = j / 384, k = j % 384;
        Wlt[j] = (n < 96) ? f2bf(Wl[(size_t)k * 96 + n]) : (unsigned short)0;
    }
}

// ================= fused BN-finalize + weight-fold kernels =================
__global__ void bnfold_a(const float* __restrict__ csum, const float* __restrict__ csq,
                         const float* __restrict__ gamma, const float* __restrict__ beta,
                         const float* __restrict__ Wa, const float* __restrict__ ba,
                         unsigned short* __restrict__ Wat2, float* __restrict__ ba_f) {
    __shared__ float scl[96], shf[96];
    int tid = threadIdx.x;
    if (tid < 96) {
        float mu  = csum[tid] / (float)NNODES;
        float var = csq[tid] / (float)NNODES - mu * mu;
        if (var < 0.f) var = 0.f;
        float sc = gamma[tid] * rsqrtf(var + 1e-5f);
        scl[tid] = sc; shf[tid] = beta[tid] - mu * sc;
    }
    __syncthreads();
    for (int idx = tid; idx < 128 * 96; idx += 256) {
        int n = idx / 96, k = idx % 96;
        Wat2[idx] = (n < 96) ? f2bf(scl[k] * Wa[k * 96 + n]) : (unsigned short)0;
    }
    if (tid < 96) {
        float s = ba[tid];
        for (int k = 0; k < 96; ++k) s += shf[k] * Wa[k * 96 + tid];
        ba_f[tid] = s;
    }
}

__global__ void bnfold_b(const float* __restrict__ csum, const float* __restrict__ csq,
                         const float* __restrict__ gamma, const float* __restrict__ beta,
                         const float* __restrict__ Wb, const float* __restrict__ bb,
                         unsigned short* __restrict__ Wbt, float* __restrict__ bb_f) {
    __shared__ float scl[96], shf[96];
    int tid = threadIdx.x;
    if (tid < 96) {
        float mu  = csum[tid] / (float)NNODES;
        float var = csq[tid] / (float)NNODES - mu * mu;
        if (var < 0.f) var = 0.f;
        float sc = gamma[tid] * rsqrtf(var + 1e-5f);
        scl[tid] = sc; shf[tid] = beta[tid] - mu * sc;
    }
    __syncthreads();
    for (int idx = tid; idx < 64 * 96; idx += 256) {
        int n = idx / 96, k = idx % 96;
        Wbt[idx] = (n < 2) ? f2bf(scl[k] * Wb[k * 2 + n]) : (unsigned short)0;
    }
    if (tid < 2) {
        float s = bb[tid];
        for (int k = 0; k < 96; ++k) s += shf[k] * Wb[k * 2 + tid];
        bb_f[tid] = s;
    }
}

__global__ void bn_fin_apply(const float* __restrict__ csum, const float* __restrict__ csq,
                             const float* __restrict__ gamma, const float* __restrict__ beta,
                             float* __restrict__ y, int total) {
    int i = blockIdx.x * blockDim.x + threadIdx.x;
    if (i >= total) return;
    int j = i & 1;
    float mu  = csum[j] / (float)NNODES;
    float var = csq[j] / (float)NNODES - mu * mu;
    if (var < 0.f) var = 0.f;
    float sc = gamma[j] * rsqrtf(var + 1e-5f);
    float sh = beta[j] - mu * sc;
    y[i] = y[i] * sc + sh;
}

__device__ __forceinline__ void edge_src_dst(const int* ei, int e, int& src, int& dst) {
    if (e < NEDGES) { src = ei[e]; dst = ei[NEDGES + e]; }
    else { src = e - NEDGES; dst = src; }
}

// ================= CSR build =================
__global__ __launch_bounds__(256) void csr_count(const int* __restrict__ ei, int* __restrict__ cnt) {
    int e = blockIdx.x * blockDim.x + threadIdx.x;
    if (e >= ETOT) return;
    int src, dst; edge_src_dst(ei, e, src, dst); (void)src;
    atomicAdd(&cnt[dst], 1);
}

#define SCAN_CH 1024
#define SCAN_NB ((NNODES + SCAN_CH - 1) / SCAN_CH)   // 49

__global__ __launch_bounds__(256) void scan1(const int* __restrict__ cnt, int* __restrict__ part) {
    int t = threadIdx.x;
    int base = blockIdx.x * SCAN_CH + t * 4;
    int4 v = {0, 0, 0, 0};
    if (base + 3 < NNODES) v = *(const int4*)(cnt + base);
    else {
        if (base + 0 < NNODES) v.x = cnt[base + 0];
        if (base + 1 < NNODES) v.y = cnt[base + 1];
        if (base + 2 < NNODES) v.z = cnt[base + 2];
        if (base + 3 < NNODES) v.w = cnt[base + 3];
    }
    int s = v.x + v.y + v.z + v.w;
    __shared__ int sm[256];
    sm[t] = s;
    __syncthreads();
    for (int off = 128; off > 0; off >>= 1) {
        if (t < off) sm[t] += sm[t + off];
        __syncthreads();
    }
    if (t == 0) part[blockIdx.x] = sm[0];
}

__global__ void scan2(int* __restrict__ part, int* __restrict__ rowstart) {
    int lane = threadIdx.x;
    int v = (lane < SCAN_NB) ? part[lane] : 0;
    #pragma unroll
    for (int off = 1; off < 64; off <<= 1) {
        int t = __shfl_up(v, off);
        if (lane >= off) v += t;
    }
    int ex = __shfl_up(v, 1);
    if (lane == 0) ex = 0;
    if (lane < SCAN_NB) part[lane] = ex;
    if (lane == 0) rowstart[NNODES] = ETOT;
}

__global__ __launch_bounds__(256) void scan3(const int* __restrict__ cnt, const int* __restrict__ part,
                                             int* __restrict__ rowstart, int* __restrict__ cursor) {
    int t = threadIdx.x;
    int base = blockIdx.x * SCAN_CH + t * 4;
    int4 v = {0, 0, 0, 0};
    if (base + 3 < NNODES) v = *(const int4*)(cnt + base);
    else {
        if (base + 0 < NNODES) v.x = cnt[base + 0];
        if (base + 1 < NNODES) v.y = cnt[base + 1];
        if (base + 2 < NNODES) v.z = cnt[base + 2];
        if (base + 3 < NNODES) v.w = cnt[base + 3];
    }
    int s = v.x + v.y + v.z + v.w;
    __shared__ int sm[2][256];
    sm[0][t] = s;
    __syncthreads();
    int cur = 0;
    #pragma unroll
    for (int off = 1; off < 256; off <<= 1) {
        int nxt = cur ^ 1;
        int val = sm[cur][t];
        if (t >= off) val += sm[cur][t - off];
        sm[nxt][t] = val;
        __syncthreads();
        cur = nxt;
    }
    int p = sm[cur][t] - s + part[blockIdx.x];
    if (base + 0 < NNODES) { rowstart[base + 0] = p; cursor[base + 0] = p; } p += v.x;
    if (base + 1 < NNODES) { rowstart[base + 1] = p; cursor[base + 1] = p; } p += v.y;
    if (base + 2 < NNODES) { rowstart[base + 2] = p; cursor[base + 2] = p; } p += v.z;
    if (base + 3 < NNODES) { rowstart[base + 3] = p; cursor[base + 3] = p; }
}

__global__ __launch_bounds__(256) void csr_fill(const int* __restrict__ ei,
                                                int* __restrict__ cursor,
                                                int* __restrict__ esrc) {
    int e = blockIdx.x * blockDim.x + threadIdx.x;
    if (e >= ETOT) return;
    int src, dst; edge_src_dst(ei, e, src, dst);
    int pos = atomicAdd(&cursor[dst], 1);
    esrc[pos] = src;
}

// ================= fused gather with deferred softmax normalization =================
// softmax(l)_i . h_i == (1/sum_j exp(l_j)) * sum_i exp(l_i) h_i  (shift-invariant; logits O(1))
// conv1 (H=2, 256 feats): 2 groups x 32 lanes x 16 B, unroll 3 (6 gathers in flight).
__global__ __launch_bounds__(256) void gat_gather_h2(
    const int* __restrict__ rowstart, const int* __restrict__ esrc,
    const unsigned short* __restrict__ hb, const float* __restrict__ a_src,
    const float* __restrict__ a_dst, const float* __restrict__ bias,
    unsigned short* __restrict__ xcat)
{
    int n = (blockIdx.x * blockDim.x + threadIdx.x) >> 6;
    int lane = threadIdx.x & 63;
    if (n >= NNODES) return;
    int beg = rowstart[n], deg = rowstart[n + 1] - beg;
    const int* es = esrc + beg;
    int g = lane >> 5, sl = lane & 31, head = sl >> 4;
    float adh = a_dst[n * 2 + head];

    float acc[8] = {}, acc2[8] = {}, acc3[8] = {};
    float se = 0.f;
    for (int idx = g; idx < deg; idx += 6) {        // visits idx, idx+2, idx+4 (parity g)
        int sA = es[idx];
        float lA = a_src[sA * 2 + head] + adh; lA = lA >= 0.f ? lA : 0.2f * lA;
        float wA = __expf(lA);
        const ushort8v hvA = *(const ushort8v*)(hb + (size_t)sA * 256 + sl * 8);
        int iB = idx + 2, iC = idx + 4;
        if (iB < deg) {
            int sB = es[iB];
            float lB = a_src[sB * 2 + head] + adh; lB = lB >= 0.f ? lB : 0.2f * lB;
            float wB = __expf(lB);
            const ushort8v hvB = *(const ushort8v*)(hb + (size_t)sB * 256 + sl * 8);
            se += wB;
            #pragma unroll
            for (int j = 0; j < 8; ++j) acc2[j] += wB * bf2f(hvB[j]);
        }
        if (iC < deg) {
            int sC = es[iC];
            float lC = a_src[sC * 2 + head] + adh; lC = lC >= 0.f ? lC : 0.2f * lC;
            float wC = __expf(lC);
            const ushort8v hvC = *(const ushort8v*)(hb + (size_t)sC * 256 + sl * 8);
            se += wC;
            #pragma unroll
            for (int j = 0; j < 8; ++j) acc3[j] += wC * bf2f(hvC[j]);
        }
        se += wA;
        #pragma unroll
        for (int j = 0; j < 8; ++j) acc[j] += wA * bf2f(hvA[j]);
    }
    #pragma unroll
    for (int j = 0; j < 8; ++j) acc[j] += acc2[j] + acc3[j];
    #pragma unroll
    for (int j = 0; j < 8; ++j) acc[j] += __shfl_xor(acc[j], 32);
    se += __shfl_xor(se, 32);                       // other parity group, same head
    float inv = 1.f / (se + 1e-16f);
    if (g == 0) {
        ushort8v o;
        #pragma unroll
        for (int j = 0; j < 8; ++j) o[j] = f2bf(acc[j] * inv + bias[sl * 8 + j]);
        *(ushort8v*)(xcat + (size_t)n * 384 + sl * 8) = o;
    }
}

// conv2 (H=1, 128 feats): 4 groups x 16 lanes x 16 B, unroll 2 (8 gathers in flight).
__global__ __launch_bounds__(256) void gat_gather_h1(
    const int* __restrict__ rowstart, const int* __restrict__ esrc,
    const unsigned short* __restrict__ hb, const float* __restrict__ a_src,
    const float* __restrict__ a_dst, const float* __restrict__ bias,
    unsigned short* __restrict__ xcat)
{
    int n = (blockIdx.x * blockDim.x + threadIdx.x) >> 6;
    int lane = threadIdx.x & 63;
    if (n >= NNODES) return;
    int beg = rowstart[n], deg = rowstart[n + 1] - beg;
    const int* es = esrc + beg;
    int g = lane >> 4, sl = lane & 15;
    float ad0 = a_dst[n];

    float acc[8] = {}, acc2[8] = {};
    float se = 0.f;
    for (int idx = g; idx < deg; idx += 8) {        // visits idx, idx+4 (idx ≡ g mod 4)
        int sA = es[idx];
        float lA = a_src[sA] + ad0; lA = lA >= 0.f ? lA : 0.2f * lA;
        float wA = __expf(lA);
        const ushort8v hvA = *(const ushort8v*)(hb + (size_t)sA * 128 + sl * 8);
        int iB = idx + 4;
        if (iB < deg) {
            int sB = es[iB];
            float lB = a_src[sB] + ad0; lB = lB >= 0.f ? lB : 0.2f * lB;
            float wB = __expf(lB);
            const ushort8v hvB = *(const ushort8v*)(hb + (size_t)sB * 128 + sl * 8);
            se += wB;
            #pragma unroll
            for (int j = 0; j < 8; ++j) acc2[j] += wB * bf2f(hvB[j]);
        }
        se += wA;
        #pragma unroll
        for (int j = 0; j < 8; ++j) acc[j] += wA * bf2f(hvA[j]);
    }
    #pragma unroll
    for (int j = 0; j < 8; ++j) acc[j] += acc2[j];
    #pragma unroll
    for (int j = 0; j < 8; ++j) acc[j] += __shfl_xor(acc[j], 16);
    se += __shfl_xor(se, 16);
    #pragma unroll
    for (int j = 0; j < 8; ++j) acc[j] += __shfl_xor(acc[j], 32);
    se += __shfl_xor(se, 32);
    float inv = 1.f / (se + 1e-16f);
    if (g == 0) {
        ushort8v o;
        #pragma unroll
        for (int j = 0; j < 8; ++j) o[j] = f2bf(acc[j] * inv + bias[sl * 8 + j]);
        *(ushort8v*)(xcat + (size_t)n * 384 + 256 + sl * 8) = o;
    }
}

extern "C" void kernel_launch(void* const* d_in, const int* in_sizes, int n_in,
                              void* d_out, int out_size, void* d_ws, size_t ws_size,
                              hipStream_t stream) {
    const float* x        = (const float*)d_in[0];
    const int*   ei       = (const int*)d_in[1];
    const float* W1       = (const float*)d_in[2];
    const float* att_src1 = (const float*)d_in[3];
    const float* att_dst1 = (const float*)d_in[4];
    const float* bias1    = (const float*)d_in[5];
    const float* W2       = (const float*)d_in[6];
    const float* att_src2 = (const float*)d_in[7];
    const float* att_dst2 = (const float*)d_in[8];
    const float* bias2    = (const float*)d_in[9];
    const float* Wl       = (const float*)d_in[10];
    const float* bl       = (const float*)d_in[11];
    const float* gl       = (const float*)d_in[12];
    const float* betal    = (const float*)d_in[13];
    const float* Wa       = (const float*)d_in[14];
    const float* ba       = (const float*)d_in[15];
    const float* ga       = (const float*)d_in[16];
    const float* betaa    = (const float*)d_in[17];
    const float* Wb       = (const float*)d_in[18];
    const float* bb       = (const float*)d_in[19];
    const float* gb       = (const float*)d_in[20];
    const float* betab    = (const float*)d_in[21];
    float* out = (float*)d_out;
    char* ws = (char*)d_ws;

    const int N = NNODES;

    // ---------- workspace layout (bytes) ----------
    const size_t offY2b  = 0;            //  9.6 MB: y2b bf16 [50000][96]
    const size_t offXcat = 19200000;     // 38.4 MB: xcat bf16 [50000][384]
    const size_t offXb   = 57600000;     // 12.8 MB: xb bf16 -> hb2 bf16 [50000][128]
    const size_t offY1b  = 70400000;     //  9.6 MB: y1b bf16 [50000][96]
    const size_t offHb1  = 80000000;     // 25.6 MB: hb1 bf16 [50000][256]
    const size_t offW1t  = 105600000;    // 64 KB
    const size_t offW2t  = 105665536;    // 64 KB
    const size_t offWlt  = 105731072;    // 96 KB
    const size_t offWat2 = 105829376;    // folded Wa bf16 [128][96]
    const size_t offWbt  = 105853952;    // folded Wb bf16 [64][96]
    const size_t offBaf  = 105866240;    // folded ba [96] f32
    const size_t offBbf  = 105866640;    // folded bb [2] f32
    const size_t offRow  = 106000000;    // cnt -> rowstart [N+1] ints
    const size_t offCur  = 106200128;    // cursor [N] ints
    const size_t offEsrc = 106400832;    // esrc [ETOT] ints
    const size_t offPart = 108700000;    // scan partials [64] ints
    const size_t offAs1  = 108800000;    // a_src1 [N*2] f32
    const size_t offAd1  = 109200000;
    const size_t offAs2  = 109600000;
    const size_t offAd2  = 109800000;
    const size_t offSt   = 110000000;    // stats

    unsigned short* y2b  = (unsigned short*)(ws + offY2b);
    unsigned short* xcat = (unsigned short*)(ws + offXcat);
    unsigned short* xb   = (unsigned short*)(ws + offXb);
    unsigned short* hb2  = (unsigned short*)(ws + offXb);
    unsigned short* y1b  = (unsigned short*)(ws + offY1b);
    unsigned short* hb1  = (unsigned short*)(ws + offHb1);
    unsigned short* W1t  = (unsigned short*)(ws + offW1t);
    unsigned short* W2t  = (unsigned short*)(ws + offW2t);
    unsigned short* Wlt  = (unsigned short*)(ws + offWlt);
    unsigned short* Wat2 = (unsigned short*)(ws + offWat2);
    unsigned short* Wbt  = (unsigned short*)(ws + offWbt);
    float* ba_f = (float*)(ws + offBaf);
    float* bb_f = (float*)(ws + offBbf);
    int* rowst  = (int*)(ws + offRow);
    int* cursor = (int*)(ws + offCur);
    int* esrc   = (int*)(ws + offEsrc);
    int* part   = (int*)(ws + offPart);
    float* as1  = (float*)(ws + offAs1);
    float* ad1  = (float*)(ws + offAd1);
    float* as2  = (float*)(ws + offAs2);
    float* ad2  = (float*)(ws + offAd2);

    float* csum_l = (float*)(ws + offSt + 0);
    float* csq_l  = (float*)(ws + offSt + 512);
    float* csum_a = (float*)(ws + offSt + 2048);
    float* csq_a  = (float*)(ws + offSt + 2560);
    float* csum_b = (float*)(ws + offSt + 4096);
    float* csq_b  = (float*)(ws + offSt + 4608);

    hipMemsetAsync(ws + offRow, 0, (NNODES + 1) * sizeof(int), stream);
    hipMemsetAsync(ws + offAs1, 0, (offSt + 6144) - offAs1, stream);

    dim3 blk(256);
    int edgeBlocks  = (ETOT + 255) / 256;
    int waveBlocksN = (N + 3) / 4;

    // ---- casts ----
    cast_x_k<<<(N * 128 / 4 + 255) / 256, blk, 0, stream>>>(x, xb, N * 128 / 4);
    cast_weights<<<(114688 + 255) / 256, blk, 0, stream>>>(W1, W2, Wl, W1t, W2t, Wlt);

    // ---- CSR build ----
    csr_count<<<edgeBlocks, blk, 0, stream>>>(ei, rowst);
    scan1<<<SCAN_NB, blk, 0, stream>>>(rowst, part);
    scan2<<<1, 64, 0, stream>>>(part, rowst);
    scan3<<<SCAN_NB, blk, 0, stream>>>(rowst, part, rowst, cursor);
    csr_fill<<<edgeBlocks, blk, 0, stream>>>(ei, cursor, esrc);

    // ---- conv1: hb1 = bf16(xb @ W1), fused att dots; fused gather ----
    gemm_mfma<<<dim3(4, (N + GBM - 1) / GBM), blk, 0, stream>>>(
        xb, 128, W1t, nullptr, hb1, nullptr, nullptr, nullptr,
        att_src1, att_dst1, as1, ad1, 2, N, 256, 128, 0);
    gat_gather_h2<<<waveBlocksN, blk, 0, stream>>>(rowst, esrc, hb1, as1, ad1, bias1, xcat);

    // ---- conv2: hb2 = bf16(xcat[:, :256] @ W2), fused att dots; fused gather ----
    gemm_mfma<<<dim3(2, (N + GBM - 1) / GBM), blk, 0, stream>>>(
        xcat, 384, W2t, nullptr, hb2, nullptr, nullptr, nullptr,
        att_src2, att_dst2, as2, ad2, 1, N, 128, 256, 0);
    gat_gather_h1<<<waveBlocksN, blk, 0, stream>>>(rowst, esrc, hb2, as2, ad2, bias2, xcat);

    // ---- lin1: y1b = bf16(relu(xcat @ Wl + bl)), stats; fold BN into Wa ----
    gemm_mfma<<<dim3(2, (N + GBM - 1) / GBM), blk, 0, stream>>>(
        xcat, 384, Wlt, nullptr, y1b, bl, csum_l, csq_l,
        nullptr, nullptr, nullptr, nullptr, 0, N, 96, 384, 1);
    bnfold_a<<<1, 256, 0, stream>>>(csum_l, csq_l, gl, betal, Wa, ba, Wat2, ba_f);

    // ---- mlp1 layer 1: y2b = bf16(relu(y1b @ Wa' + ba')), stats; fold BN into Wb ----
    gemm_mfma<<<dim3(2, (N + GBM - 1) / GBM), blk, 0, stream>>>(
        y1b, 96, Wat2, nullptr, y2b, ba_f, csum_a, csq_a,
        nullptr, nullptr, nullptr, nullptr, 0, N, 96, 96, 1);
    bnfold_b<<<1, 256, 0, stream>>>(csum_a, csq_a, ga, betaa, Wb, bb, Wbt, bb_f);

    // ---- mlp1 layer 2: out = relu(y2b @ Wb' + bb'), stats (MFMA, N=2) ----
    gemm_mfma<<<dim3(1, (N + GBM - 1) / GBM), blk, 0, stream>>>(
        y2b, 96, Wbt, out, nullptr, bb_f, csum_b, csq_b,
        nullptr, nullptr, nullptr, nullptr, 0, N, 2, 96, 1);

    // ---- final BN (fused finalize+apply) ----
    bn_fin_apply<<<(N * 2 + 255) / 256, blk, 0, stream>>>(csum_b, csq_b, gb, betab, out, N * 2);
}